// Round 1
// baseline (3491.872 us; speedup 1.0000x reference)
//
#include <hip/hip_runtime.h>
#include <math.h>

constexpr float DECAY = 0.99f;
constexpr float EPS_F = 1e-5f;

// ---------------- kernel 1: e2[k] = sum_d e[d,k]^2  (f64)
__global__ void k_enorm(const float* __restrict__ e, double* __restrict__ e2,
                        int D, int K) {
  int k = blockIdx.x * blockDim.x + threadIdx.x;
  if (k >= K) return;
  double s = 0.0;
  for (int d = 0; d < D; ++d) {
    double v = (double)e[(size_t)d * K + k];
    s = fma(v, v, s);
  }
  e2[k] = s;
}

// ---------------- kernel 2: per-row argmin_k ( ||e_k||^2 - 2 x.e_k ), f64 accum
#define AM_ROWS 128   // rows per block
#define AM_KS   128   // codes per k-tile
#define AM_RT   8     // rows per thread
#define AM_KT   8     // codes per thread
#define AM_DSTEP 16   // d-slice staged in LDS

__launch_bounds__(256, 1)
__global__ void k_argmin(const float* __restrict__ x, const float* __restrict__ e,
                         const double* __restrict__ e2,
                         int* __restrict__ idx_out, float* __restrict__ idxf_out,
                         unsigned int* __restrict__ cnt,
                         int D, int K) {
  __shared__ float  xs[AM_DSTEP][AM_ROWS + 4];  // +4 pad: avoid 16-way store conflict
  __shared__ double es[AM_DSTEP][AM_KS];

  const int tid = threadIdx.x;
  const int tx = tid & 15;          // code group
  const int ty = tid >> 4;          // row group
  const int row0 = blockIdx.x * AM_ROWS;

  double best[AM_RT];
  int    bidx[AM_RT];
#pragma unroll
  for (int r = 0; r < AM_RT; ++r) { best[r] = 1e300; bidx[r] = 0; }

  for (int k0 = 0; k0 < K; k0 += AM_KS) {
    double acc[AM_RT][AM_KT];
#pragma unroll
    for (int r = 0; r < AM_RT; ++r)
#pragma unroll
      for (int j = 0; j < AM_KT; ++j) acc[r][j] = 0.0;

    for (int dd = 0; dd < D; dd += AM_DSTEP) {
      __syncthreads();  // protect previous slice's reads
      // stage X slice: 16 d x 128 rows
#pragma unroll
      for (int p = 0; p < (AM_DSTEP * AM_ROWS) / 256; ++p) {
        int i = tid + p * 256;
        int d = i & (AM_DSTEP - 1);
        int r = i >> 4;
        xs[d][r] = x[(size_t)(row0 + r) * D + dd + d];
      }
      // stage E slice with f64 conversion: 16 d x 128 codes
#pragma unroll
      for (int p = 0; p < (AM_DSTEP * AM_KS) / 256; ++p) {
        int i = tid + p * 256;
        int d = i >> 7;
        int k = i & (AM_KS - 1);
        es[d][k] = (double)e[(size_t)(dd + d) * K + k0 + k];
      }
      __syncthreads();

#pragma unroll
      for (int d = 0; d < AM_DSTEP; ++d) {
        double ev[AM_KT];
#pragma unroll
        for (int j = 0; j < AM_KT; ++j) ev[j] = es[d][tx + 16 * j];
        const float4 xa = *(const float4*)&xs[d][ty * AM_RT];
        const float4 xb = *(const float4*)&xs[d][ty * AM_RT + 4];
        const float xv[8] = {xa.x, xa.y, xa.z, xa.w, xb.x, xb.y, xb.z, xb.w};
#pragma unroll
        for (int r = 0; r < AM_RT; ++r) {
          const double xd = (double)xv[r];
#pragma unroll
          for (int j = 0; j < AM_KT; ++j)
            acc[r][j] = fma(xd, ev[j], acc[r][j]);
        }
      }
    }

    // fold this k-tile into running best (k ascending within thread)
#pragma unroll
    for (int r = 0; r < AM_RT; ++r) {
#pragma unroll
      for (int j = 0; j < AM_KT; ++j) {
        int k = k0 + tx + 16 * j;
        double score = e2[k] - 2.0 * acc[r][j];
        if (score < best[r] || (score == best[r] && k < bidx[r])) {
          best[r] = score; bidx[r] = k;
        }
      }
    }
  }

  // reduce across the 16 tx lanes (same 16-lane group within the wave)
#pragma unroll
  for (int off = 1; off < 16; off <<= 1) {
#pragma unroll
    for (int r = 0; r < AM_RT; ++r) {
      double ov = __shfl_xor(best[r], off, 64);
      int    oi = __shfl_xor(bidx[r], off, 64);
      if (ov < best[r] || (ov == best[r] && oi < bidx[r])) {
        best[r] = ov; bidx[r] = oi;
      }
    }
  }

  if (tx == 0) {
#pragma unroll
    for (int r = 0; r < AM_RT; ++r) {
      int row = row0 + ty * AM_RT + r;
      idx_out[row] = bidx[r];
      idxf_out[row] = (float)bidx[r];
      atomicAdd(&cnt[bidx[r]], 1u);
    }
  }
}

// ---------------- kernel 3: cluster_size_new, n, smoothed cs
__global__ void k_cluster(const float* __restrict__ cs_in,
                          const unsigned int* __restrict__ cnt,
                          float* __restrict__ out_csn, float* __restrict__ cs_ws,
                          int K) {
  __shared__ double red[256];
  const int tid = threadIdx.x;
  double s = 0.0;
  for (int k = tid; k < K; k += 256) {
    float csn = cs_in[k] * DECAY + (float)cnt[k] * (1.0f - EPS_F);
    out_csn[k] = csn;
    s += (double)csn;
  }
  red[tid] = s;
  __syncthreads();
  for (int off = 128; off > 0; off >>= 1) {
    if (tid < off) red[tid] += red[tid + off];
    __syncthreads();
  }
  const float n = (float)red[0];
  const float denom = n + (float)K * EPS_F;
  for (int k = tid; k < K; k += 256) {
    float csn = out_csn[k];
    float cs = (csn + EPS_F) / denom * n;
    cs_ws[k] = cs;
  }
}

// ---------------- kernel 4: embed_avg_new = avg*decay ; embed_new = avg_new / cs
__global__ void k_embed(const float* __restrict__ avg_in, const float* __restrict__ cs_ws,
                        float* __restrict__ out_avg, float* __restrict__ out_emb, int K) {
  int k = blockIdx.x * blockDim.x + threadIdx.x;
  int d = blockIdx.y;
  if (k >= K) return;
  size_t i = (size_t)d * K + k;
  float a = avg_in[i] * DECAY;
  out_avg[i] = a;
  out_emb[i] = a / cs_ws[k];
}

// ---------------- kernel 5: gather quantize + straight-through + per-row diff partial
__global__ void k_gather(const float* __restrict__ x, const float* __restrict__ emb,
                         const int* __restrict__ idx, float* __restrict__ out_q,
                         float* __restrict__ partial, int D, int K) {
  __shared__ float red[256];
  const int n = blockIdx.x;
  const int tid = threadIdx.x;
  const int code = idx[n];
  float s = 0.f;
  for (int d = tid; d < D; d += 256) {
    float q = emb[(size_t)d * K + code];
    float xv = x[(size_t)n * D + d];
    out_q[(size_t)n * D + d] = xv + (q - xv);   // straight-through value
    float dv = q - xv;
    s += dv * dv;
  }
  red[tid] = s;
  __syncthreads();
  for (int off = 128; off > 0; off >>= 1) {
    if (tid < off) red[tid] += red[tid + off];
    __syncthreads();
  }
  if (tid == 0) partial[n] = red[0];
}

// ---------------- kernel 6: diff = mean
__global__ void k_diff(const float* __restrict__ partial, float* __restrict__ out_diff,
                       int N, int D) {
  __shared__ double red[256];
  const int tid = threadIdx.x;
  double s = 0.0;
  for (int i = tid; i < N; i += 256) s += (double)partial[i];
  red[tid] = s;
  __syncthreads();
  for (int off = 128; off > 0; off >>= 1) {
    if (tid < off) red[tid] += red[tid + off];
    __syncthreads();
  }
  if (tid == 0) out_diff[0] = (float)(red[0] / ((double)N * (double)D));
}

extern "C" void kernel_launch(void* const* d_in, const int* in_sizes, int n_in,
                              void* d_out, int out_size, void* d_ws, size_t ws_size,
                              hipStream_t stream) {
  const float* x            = (const float*)d_in[0];
  const float* embed        = (const float*)d_in[1];
  const float* cluster_size = (const float*)d_in[2];
  const float* embed_avg    = (const float*)d_in[3];

  const int K = in_sizes[2];
  const int D = in_sizes[1] / K;
  const int N = in_sizes[0] / D;

  float* out      = (float*)d_out;
  float* out_q    = out;                          // N*D
  float* out_idx  = out_q + (size_t)N * D;        // N (indices as float)
  float* out_diff = out_idx + N;                  // 1
  float* out_csn  = out_diff + 1;                 // K
  float* out_avg  = out_csn + K;                  // D*K
  float* out_emb  = out_avg + (size_t)D * K;      // D*K

  double*       e2      = (double*)d_ws;          // K
  int*          idx     = (int*)(e2 + K);         // N
  unsigned int* cnt     = (unsigned int*)(idx + N); // K
  float*        cs_ws   = (float*)(cnt + K);      // K
  float*        partial = cs_ws + K;              // N

  hipMemsetAsync(cnt, 0, (size_t)K * sizeof(unsigned int), stream);

  k_enorm<<<dim3((K + 255) / 256), dim3(256), 0, stream>>>(embed, e2, D, K);
  k_argmin<<<dim3(N / AM_ROWS), dim3(256), 0, stream>>>(x, embed, e2, idx, out_idx, cnt, D, K);
  k_cluster<<<dim3(1), dim3(256), 0, stream>>>(cluster_size, cnt, out_csn, cs_ws, K);
  k_embed<<<dim3((K + 255) / 256, D), dim3(256), 0, stream>>>(embed_avg, cs_ws, out_avg, out_emb, K);
  k_gather<<<dim3(N), dim3(256), 0, stream>>>(x, out_emb, idx, out_q, partial, D, K);
  k_diff<<<dim3(1), dim3(256), 0, stream>>>(partial, out_diff, N, D);
}

// Round 2
// 3213.456 us; speedup vs baseline: 1.0866x; 1.0866x over previous
//
#include <hip/hip_runtime.h>
#include <math.h>

constexpr float DECAY = 0.99f;
constexpr float EPS_F = 1e-5f;
constexpr float MARGIN = 0.05f;   // f32 err bound ~1e-3 each side; 25x headroom

// ---------------- kernel 1: e2[k] = sum_d e[d,k]^2  (f64 exact + f32 copy)
__global__ void k_enorm(const float* __restrict__ e, double* __restrict__ e2d,
                        float* __restrict__ e2f, int D, int K) {
  int k = blockIdx.x * blockDim.x + threadIdx.x;
  if (k >= K) return;
  double s = 0.0;
  for (int d = 0; d < D; ++d) {
    double v = (double)e[(size_t)d * K + k];
    s = fma(v, v, s);
  }
  e2d[k] = s;
  e2f[k] = (float)s;
}

// ---------------- kernel 2: f32 top-2 argmin over a K-slice
#define BM 128      // rows per block
#define BK 256      // codes per k-tile
#define DSTEP 16
#define KSPLIT 2

__launch_bounds__(256, 2)
__global__ void k_argmin_f32(const float* __restrict__ x, const float* __restrict__ e,
                             const float* __restrict__ e2f,
                             float* __restrict__ bestv, float* __restrict__ secv,
                             int* __restrict__ besti, int D, int K, int N) {
  __shared__ float xs[DSTEP][BM + 4];
  __shared__ float es[DSTEP][BK];

  const int tid = threadIdx.x;
  const int tx = tid & 15;
  const int ty = tid >> 4;
  const int row0 = blockIdx.x * BM;
  const int kslice = K / KSPLIT;
  const int kbase = blockIdx.y * kslice;

  float best[8], sec[8];
  int bidx[8];
#pragma unroll
  for (int r = 0; r < 8; ++r) { best[r] = 3e38f; sec[r] = 3e38f; bidx[r] = 0; }

  for (int kt = 0; kt < kslice; kt += BK) {
    const int k0 = kbase + kt;
    float acc[8][16];
#pragma unroll
    for (int r = 0; r < 8; ++r)
#pragma unroll
      for (int j = 0; j < 16; ++j) acc[r][j] = 0.f;

    for (int dd = 0; dd < D; dd += DSTEP) {
      __syncthreads();
      // stage X slice transposed: 16 d x 128 rows
      {
        const int r = tid >> 1;
        const int dh = (tid & 1) * 8;
        const float4 a = *(const float4*)&x[(size_t)(row0 + r) * D + dd + dh];
        const float4 b = *(const float4*)&x[(size_t)(row0 + r) * D + dd + dh + 4];
        xs[dh + 0][r] = a.x; xs[dh + 1][r] = a.y; xs[dh + 2][r] = a.z; xs[dh + 3][r] = a.w;
        xs[dh + 4][r] = b.x; xs[dh + 5][r] = b.y; xs[dh + 6][r] = b.z; xs[dh + 7][r] = b.w;
      }
      // stage E slice: 16 d x 256 codes (row-major, b128)
      {
        const int d = tid >> 4;
        const int kk = (tid & 15) * 16;
        const float* src = &e[(size_t)(dd + d) * K + k0 + kk];
#pragma unroll
        for (int q = 0; q < 4; ++q)
          *(float4*)&es[d][kk + q * 4] = *(const float4*)&src[q * 4];
      }
      __syncthreads();

#pragma unroll
      for (int d = 0; d < DSTEP; ++d) {
        float2 ev[8];
#pragma unroll
        for (int j = 0; j < 8; ++j)
          ev[j] = *(const float2*)&es[d][2 * tx + 32 * j];
        const float4 xa = *(const float4*)&xs[d][ty * 8];
        const float4 xb = *(const float4*)&xs[d][ty * 8 + 4];
        const float xv[8] = {xa.x, xa.y, xa.z, xa.w, xb.x, xb.y, xb.z, xb.w};
#pragma unroll
        for (int r = 0; r < 8; ++r) {
#pragma unroll
          for (int j = 0; j < 8; ++j) {
            acc[r][2 * j]     = fmaf(xv[r], ev[j].x, acc[r][2 * j]);
            acc[r][2 * j + 1] = fmaf(xv[r], ev[j].y, acc[r][2 * j + 1]);
          }
        }
      }
    }

    // fold this k-tile into running top-2
#pragma unroll
    for (int j = 0; j < 8; ++j) {
      const float2 e2v = *(const float2*)&e2f[k0 + 2 * tx + 32 * j];
      const int ka = k0 + 2 * tx + 32 * j;
#pragma unroll
      for (int r = 0; r < 8; ++r) {
        float d0 = e2v.x - 2.f * acc[r][2 * j];
        float d1 = e2v.y - 2.f * acc[r][2 * j + 1];
        if (d0 < best[r] || (d0 == best[r] && ka < bidx[r])) {
          sec[r] = best[r]; best[r] = d0; bidx[r] = ka;
        } else sec[r] = fminf(sec[r], d0);
        if (d1 < best[r] || (d1 == best[r] && ka + 1 < bidx[r])) {
          sec[r] = best[r]; best[r] = d1; bidx[r] = ka + 1;
        } else sec[r] = fminf(sec[r], d1);
      }
    }
  }

  // merge top-2 across the 16 tx lanes
#pragma unroll
  for (int off = 1; off < 16; off <<= 1) {
#pragma unroll
    for (int r = 0; r < 8; ++r) {
      float ob = __shfl_xor(best[r], off);
      float os = __shfl_xor(sec[r], off);
      int   oi = __shfl_xor(bidx[r], off);
      if (ob < best[r] || (ob == best[r] && oi < bidx[r])) {
        sec[r] = fminf(best[r], os); best[r] = ob; bidx[r] = oi;
      } else {
        sec[r] = fminf(sec[r], ob);
      }
    }
  }

  if (tx == 0) {
    const size_t base = (size_t)blockIdx.y * N;
#pragma unroll
    for (int r = 0; r < 8; ++r) {
      int row = row0 + ty * 8 + r;
      bestv[base + row] = best[r];
      secv[base + row]  = sec[r];
      besti[base + row] = bidx[r];
    }
  }
}

// ---------------- kernel 3: combine K-slices, flag ambiguous rows
__global__ void k_combine(const float* __restrict__ bestv, const float* __restrict__ secv,
                          const int* __restrict__ besti, int* __restrict__ idx_out,
                          int* __restrict__ list, unsigned int* __restrict__ count, int N) {
  int n = blockIdx.x * blockDim.x + threadIdx.x;
  if (n >= N) return;
  float b = bestv[n], s = secv[n];
  int bi = besti[n];
#pragma unroll
  for (int p = 1; p < KSPLIT; ++p) {
    float ob = bestv[(size_t)p * N + n];
    float os = secv[(size_t)p * N + n];
    int   oi = besti[(size_t)p * N + n];
    if (ob < b || (ob == b && oi < bi)) { s = fminf(b, os); b = ob; bi = oi; }
    else s = fminf(s, ob);
  }
  idx_out[n] = bi;
  if (s - b < MARGIN) {
    unsigned int p = atomicAdd(count, 1u);
    list[p] = n;
  }
}

// ---------------- kernel 4: exact f64 rescan of flagged rows
__global__ void k_rescan(const float* __restrict__ x, const float* __restrict__ e,
                         const double* __restrict__ e2d, const int* __restrict__ list,
                         const unsigned int* __restrict__ count, int* __restrict__ idx_out,
                         int D, int K) {
  __shared__ float xrow[256];
  __shared__ double rv[256];
  __shared__ int ri[256];
  const int tid = threadIdx.x;
  const unsigned int cnt = *count;
  for (unsigned int ii = blockIdx.x; ii < cnt; ii += gridDim.x) {
    const int row = list[ii];
    __syncthreads();
    for (int d = tid; d < D; d += 256) xrow[d] = x[(size_t)row * D + d];
    __syncthreads();
    double bb = 1e300; int bi = 0;
    for (int j = 0; j < K; j += 256) {
      const int k = j + tid;
      double dot = 0.0;
      for (int d = 0; d < D; ++d)
        dot = fma((double)xrow[d], (double)e[(size_t)d * K + k], dot);
      double dist = e2d[k] - 2.0 * dot;
      if (dist < bb || (dist == bb && k < bi)) { bb = dist; bi = k; }
    }
    rv[tid] = bb; ri[tid] = bi;
    __syncthreads();
    for (int off = 128; off > 0; off >>= 1) {
      if (tid < off) {
        if (rv[tid + off] < rv[tid] || (rv[tid + off] == rv[tid] && ri[tid + off] < ri[tid])) {
          rv[tid] = rv[tid + off]; ri[tid] = ri[tid + off];
        }
      }
      __syncthreads();
    }
    if (tid == 0) idx_out[row] = ri[0];
  }
}

// ---------------- kernel 5: histogram + float indices
__global__ void k_hist(const int* __restrict__ idx, unsigned int* __restrict__ cnt,
                       float* __restrict__ idxf_out, int N) {
  int n = blockIdx.x * blockDim.x + threadIdx.x;
  if (n >= N) return;
  int c = idx[n];
  idxf_out[n] = (float)c;
  atomicAdd(&cnt[c], 1u);
}

// ---------------- kernel 6: cluster_size_new, n, smoothed cs
__global__ void k_cluster(const float* __restrict__ cs_in,
                          const unsigned int* __restrict__ cnt,
                          float* __restrict__ out_csn, float* __restrict__ cs_ws,
                          int K) {
  __shared__ double red[256];
  const int tid = threadIdx.x;
  double s = 0.0;
  for (int k = tid; k < K; k += 256) {
    float csn = cs_in[k] * DECAY + (float)cnt[k] * (1.0f - EPS_F);
    out_csn[k] = csn;
    s += (double)csn;
  }
  red[tid] = s;
  __syncthreads();
  for (int off = 128; off > 0; off >>= 1) {
    if (tid < off) red[tid] += red[tid + off];
    __syncthreads();
  }
  const float n = (float)red[0];
  const float denom = n + (float)K * EPS_F;
  for (int k = tid; k < K; k += 256) {
    float csn = out_csn[k];
    float cs = (csn + EPS_F) / denom * n;
    cs_ws[k] = cs;
  }
}

// ---------------- kernel 7: embed_avg_new = avg*decay ; embed_new = avg_new / cs
__global__ void k_embed(const float* __restrict__ avg_in, const float* __restrict__ cs_ws,
                        float* __restrict__ out_avg, float* __restrict__ out_emb, int K) {
  int k = blockIdx.x * blockDim.x + threadIdx.x;
  int d = blockIdx.y;
  if (k >= K) return;
  size_t i = (size_t)d * K + k;
  float a = avg_in[i] * DECAY;
  out_avg[i] = a;
  out_emb[i] = a / cs_ws[k];
}

// ---------------- kernel 8: gather quantize + per-row diff partial
__global__ void k_gather(const float* __restrict__ x, const float* __restrict__ emb,
                         const int* __restrict__ idx, float* __restrict__ out_q,
                         float* __restrict__ partial, int D, int K) {
  __shared__ float red[256];
  const int n = blockIdx.x;
  const int tid = threadIdx.x;
  const int code = idx[n];
  float s = 0.f;
  for (int d = tid; d < D; d += 256) {
    float q = emb[(size_t)d * K + code];
    float xv = x[(size_t)n * D + d];
    out_q[(size_t)n * D + d] = xv + (q - xv);
    float dv = q - xv;
    s += dv * dv;
  }
  red[tid] = s;
  __syncthreads();
  for (int off = 128; off > 0; off >>= 1) {
    if (tid < off) red[tid] += red[tid + off];
    __syncthreads();
  }
  if (tid == 0) partial[n] = red[0];
}

// ---------------- kernel 9: diff = mean
__global__ void k_diff(const float* __restrict__ partial, float* __restrict__ out_diff,
                       int N, int D) {
  __shared__ double red[256];
  const int tid = threadIdx.x;
  double s = 0.0;
  for (int i = tid; i < N; i += 256) s += (double)partial[i];
  red[tid] = s;
  __syncthreads();
  for (int off = 128; off > 0; off >>= 1) {
    if (tid < off) red[tid] += red[tid + off];
    __syncthreads();
  }
  if (tid == 0) out_diff[0] = (float)(red[0] / ((double)N * (double)D));
}

extern "C" void kernel_launch(void* const* d_in, const int* in_sizes, int n_in,
                              void* d_out, int out_size, void* d_ws, size_t ws_size,
                              hipStream_t stream) {
  const float* x            = (const float*)d_in[0];
  const float* embed        = (const float*)d_in[1];
  const float* cluster_size = (const float*)d_in[2];
  const float* embed_avg    = (const float*)d_in[3];

  const int K = in_sizes[2];
  const int D = in_sizes[1] / K;
  const int N = in_sizes[0] / D;

  float* out      = (float*)d_out;
  float* out_q    = out;                          // N*D
  float* out_idx  = out_q + (size_t)N * D;        // N (indices as float)
  float* out_diff = out_idx + N;                  // 1
  float* out_csn  = out_diff + 1;                 // K
  float* out_avg  = out_csn + K;                  // D*K
  float* out_emb  = out_avg + (size_t)D * K;      // D*K

  char* ws = (char*)d_ws;
  double*       e2d     = (double*)ws;               ws += (size_t)K * 8;
  float*        e2f     = (float*)ws;                ws += (size_t)K * 4;
  int*          idx     = (int*)ws;                  ws += (size_t)N * 4;
  unsigned int* cnt     = (unsigned int*)ws;         ws += (size_t)K * 4;
  float*        cs_ws   = (float*)ws;                ws += (size_t)K * 4;
  float*        partial = (float*)ws;                ws += (size_t)N * 4;
  float*        bestv   = (float*)ws;                ws += (size_t)KSPLIT * N * 4;
  float*        secv    = (float*)ws;                ws += (size_t)KSPLIT * N * 4;
  int*          besti   = (int*)ws;                  ws += (size_t)KSPLIT * N * 4;
  int*          list    = (int*)ws;                  ws += (size_t)N * 4;
  unsigned int* count   = (unsigned int*)ws;         ws += 64;

  hipMemsetAsync(cnt, 0, (size_t)K * sizeof(unsigned int), stream);
  hipMemsetAsync(count, 0, sizeof(unsigned int), stream);

  k_enorm<<<dim3((K + 255) / 256), dim3(256), 0, stream>>>(embed, e2d, e2f, D, K);
  k_argmin_f32<<<dim3(N / BM, KSPLIT), dim3(256), 0, stream>>>(x, embed, e2f, bestv, secv,
                                                               besti, D, K, N);
  k_combine<<<dim3((N + 255) / 256), dim3(256), 0, stream>>>(bestv, secv, besti, idx,
                                                             list, count, N);
  k_rescan<<<dim3(256), dim3(256), 0, stream>>>(x, embed, e2d, list, count, idx, D, K);
  k_hist<<<dim3((N + 255) / 256), dim3(256), 0, stream>>>(idx, cnt, out_idx, N);
  k_cluster<<<dim3(1), dim3(256), 0, stream>>>(cluster_size, cnt, out_csn, cs_ws, K);
  k_embed<<<dim3((K + 255) / 256, D), dim3(256), 0, stream>>>(embed_avg, cs_ws, out_avg, out_emb, K);
  k_gather<<<dim3(N), dim3(256), 0, stream>>>(x, out_emb, idx, out_q, partial, D, K);
  k_diff<<<dim3(1), dim3(256), 0, stream>>>(partial, out_diff, N, D);
}

// Round 3
// 1810.505 us; speedup vs baseline: 1.9287x; 1.7749x over previous
//
#include <hip/hip_runtime.h>
#include <math.h>

constexpr float DECAY = 0.99f;
constexpr float EPS_F = 1e-5f;
constexpr float MARGIN = 0.08f;   // bf16-split err bound ~5e-3 per side; >8x headroom

typedef short bf16x8 __attribute__((ext_vector_type(8)));
typedef float f32x4 __attribute__((ext_vector_type(4)));

#define BM 128      // rows per block
#define BN 64       // codes per k-tile
#define KSPLIT 4    // K/KSPLIT codes scanned per block
#define D_FIX 256

__device__ __forceinline__ unsigned rne_bf16(float f) {
  unsigned u = __float_as_uint(f);
  return (u + 0x7fffu + ((u >> 16) & 1u)) >> 16;
}
// split f32 -> hi (truncated top16) | lo (RNE bf16 of remainder), packed in u32
__device__ __forceinline__ unsigned pack_hilo(float v) {
  unsigned u = __float_as_uint(v);
  unsigned hi = u & 0xffff0000u;
  float rem = v - __uint_as_float(hi);
  return hi | rne_bf16(rem);
}

// ---------------- kernel 1: e2[k] = sum_d e[d,k]^2  (f64 exact + f32 copy)
__global__ void k_enorm(const float* __restrict__ e, double* __restrict__ e2d,
                        float* __restrict__ e2f, int D, int K) {
  __shared__ double red[4][64];
  const int kl = threadIdx.x & 63;
  const int part = threadIdx.x >> 6;
  const int k = blockIdx.x * 64 + kl;
  double s = 0.0;
  for (int d = part; d < D; d += 4) {
    double v = (double)e[(size_t)d * K + k];
    s = fma(v, v, s);
  }
  red[part][kl] = s;
  __syncthreads();
  if (part == 0) {
    double t = ((red[0][kl] + red[1][kl]) + red[2][kl]) + red[3][kl];
    e2d[k] = t;
    e2f[k] = (float)t;
  }
}

// ---------------- kernel 2: MFMA bf16-split top-2 argmin over a K-slice
__launch_bounds__(256, 2)
__global__ void k_argmin_mfma(const float* __restrict__ x, const float* __restrict__ e,
                              const float* __restrict__ e2f,
                              float* __restrict__ bestv, float* __restrict__ secv,
                              int* __restrict__ besti, int N, int K) {
  // E slice: 32 d x 64 cols, packed hi|lo u32, TRANSPOSED [col][d-word],
  // 16B chunks XOR-swizzled by (col&7) for conflict-free ds_read_b128.
  __shared__ unsigned es[2][BN][32];
  __shared__ float e2s[1024];      // this block's K-slice of ||e||^2

  const int tid = threadIdx.x;
  const int w   = tid >> 6;        // wave 0..3
  const int l   = tid & 63;
  const int g   = l >> 4;          // lane group 0..3
  const int c16 = l & 15;
  const int kslice = K / KSPLIT;   // 1024
  const int kbase  = blockIdx.y * kslice;
  const int rowW   = blockIdx.x * BM + w * 32;   // wave's 32 rows

  // stage e2 slice
  for (int i = tid; i < 1024; i += 256) e2s[i] = e2f[kbase + i];

  // ---- X fragments in registers: rows rowW + m*16 + c16, d = t*32 + 8g + e
  bf16x8 xh[2][8], xl[2][8];
#pragma unroll
  for (int m = 0; m < 2; ++m) {
    const float* xr = x + (size_t)(rowW + m * 16 + c16) * D_FIX + 8 * g;
#pragma unroll
    for (int t = 0; t < 8; ++t) {
      float4 fa = *(const float4*)(xr + t * 32);
      float4 fb = *(const float4*)(xr + t * 32 + 4);
      float f[8] = {fa.x, fa.y, fa.z, fa.w, fb.x, fb.y, fb.z, fb.w};
      union { unsigned u[4]; bf16x8 v; } H, L;
#pragma unroll
      for (int p = 0; p < 4; ++p) {
        unsigned w0 = pack_hilo(f[2 * p]);
        unsigned w1 = pack_hilo(f[2 * p + 1]);
        H.u[p] = (w0 >> 16) | (w1 & 0xffff0000u);
        L.u[p] = (w0 & 0xffffu) | (w1 << 16);
      }
      xh[m][t] = H.v;
      xl[m][t] = L.v;
    }
  }

  float best[2][4], sec[2][4];
  int bidx[2][4];
#pragma unroll
  for (int m = 0; m < 2; ++m)
#pragma unroll
    for (int r = 0; r < 4; ++r) { best[m][r] = 3e38f; sec[m][r] = 3e38f; bidx[m][r] = 0; }

  // ---- staging helpers (inline): step s covers kt = s>>3 (64 cols), dd=(s&7)*32
  float la[4][4];
  const int sq  = tid & 7;                // d-quad 0..7
  const int scq = 4 * ((tid >> 3) & 15);  // col-quad 0..60
  const bool stager = (tid < 128);

#define AM_LOAD(s_)                                                            \
  if (stager) {                                                                \
    const float* src = e + (size_t)(((s_) & 7) * 32 + sq * 4) * K              \
                         + (kbase + ((s_) >> 3) * 64 + scq);                   \
    _Pragma("unroll")                                                          \
    for (int i_ = 0; i_ < 4; ++i_) {                                           \
      float4 v_ = *(const float4*)(src + (size_t)i_ * K);                      \
      la[i_][0] = v_.x; la[i_][1] = v_.y; la[i_][2] = v_.z; la[i_][3] = v_.w;  \
    }                                                                          \
  }

#define AM_WRITE(buf_)                                                         \
  if (stager) {                                                                \
    _Pragma("unroll")                                                          \
    for (int j_ = 0; j_ < 4; ++j_) {                                           \
      int col_ = scq + j_;                                                     \
      uint4 pw_;                                                               \
      pw_.x = pack_hilo(la[0][j_]); pw_.y = pack_hilo(la[1][j_]);              \
      pw_.z = pack_hilo(la[2][j_]); pw_.w = pack_hilo(la[3][j_]);              \
      *(uint4*)&es[buf_][col_][(sq ^ (col_ & 7)) * 4] = pw_;                   \
    }                                                                          \
  }

  AM_LOAD(0);
  AM_WRITE(0);
  AM_LOAD(1);
  __syncthreads();

  int buf = 0;
  const int sw = c16 & 7;

  for (int kt = 0; kt < 16; ++kt) {
    f32x4 acc[2][4];
#pragma unroll
    for (int m = 0; m < 2; ++m)
#pragma unroll
      for (int c = 0; c < 4; ++c) acc[m][c] = (f32x4){0.f, 0.f, 0.f, 0.f};

#pragma unroll
    for (int t = 0; t < 8; ++t) {
      // compute on es[buf]
#pragma unroll
      for (int c = 0; c < 4; ++c) {
        const int col = c * 16 + c16;
        const unsigned* ep = es[buf][col];
        uint4 q0 = *(const uint4*)&ep[((2 * g) ^ sw) * 4];
        uint4 q1 = *(const uint4*)&ep[((2 * g + 1) ^ sw) * 4];
        union { unsigned u[4]; bf16x8 v; } bh, bl;
        bh.u[0] = (q0.y & 0xffff0000u) | (q0.x >> 16);
        bl.u[0] = (q0.x & 0xffffu) | (q0.y << 16);
        bh.u[1] = (q0.w & 0xffff0000u) | (q0.z >> 16);
        bl.u[1] = (q0.z & 0xffffu) | (q0.w << 16);
        bh.u[2] = (q1.y & 0xffff0000u) | (q1.x >> 16);
        bl.u[2] = (q1.x & 0xffffu) | (q1.y << 16);
        bh.u[3] = (q1.w & 0xffff0000u) | (q1.z >> 16);
        bl.u[3] = (q1.z & 0xffffu) | (q1.w << 16);
#pragma unroll
        for (int m = 0; m < 2; ++m) {
          acc[m][c] = __builtin_amdgcn_mfma_f32_16x16x32_bf16(xh[m][t], bh.v, acc[m][c], 0, 0, 0);
          acc[m][c] = __builtin_amdgcn_mfma_f32_16x16x32_bf16(xh[m][t], bl.v, acc[m][c], 0, 0, 0);
          acc[m][c] = __builtin_amdgcn_mfma_f32_16x16x32_bf16(xl[m][t], bh.v, acc[m][c], 0, 0, 0);
        }
      }
      const int s = kt * 8 + t;
      if (s < 127) { AM_WRITE(buf ^ 1); }
      if (s < 126) { AM_LOAD(s + 2); }
      __syncthreads();
      buf ^= 1;
    }

    // fold k-tile into running top-2 (k ascending => strict < keeps smallest k)
#pragma unroll
    for (int c = 0; c < 4; ++c) {
      const int klocal = kt * 64 + c * 16 + c16;
      const float e2v = e2s[klocal];
      const int kg = kbase + klocal;
#pragma unroll
      for (int m = 0; m < 2; ++m)
#pragma unroll
        for (int r = 0; r < 4; ++r) {
          float dist = fmaf(-2.f, acc[m][c][r], e2v);
          if (dist < best[m][r]) { sec[m][r] = best[m][r]; best[m][r] = dist; bidx[m][r] = kg; }
          else sec[m][r] = fminf(sec[m][r], dist);
        }
    }
  }

  // merge top-2 across the 16 col lanes (same row)
#pragma unroll
  for (int off = 1; off < 16; off <<= 1) {
#pragma unroll
    for (int m = 0; m < 2; ++m)
#pragma unroll
      for (int r = 0; r < 4; ++r) {
        float ob = __shfl_xor(best[m][r], off);
        float os = __shfl_xor(sec[m][r], off);
        int   oi = __shfl_xor(bidx[m][r], off);
        if (ob < best[m][r] || (ob == best[m][r] && oi < bidx[m][r])) {
          sec[m][r] = fminf(best[m][r], os); best[m][r] = ob; bidx[m][r] = oi;
        } else {
          sec[m][r] = fminf(sec[m][r], ob);
        }
      }
  }

  if (c16 == 0) {
    const size_t base = (size_t)blockIdx.y * N;
#pragma unroll
    for (int m = 0; m < 2; ++m)
#pragma unroll
      for (int r = 0; r < 4; ++r) {
        int row = rowW + m * 16 + 4 * g + r;
        bestv[base + row] = best[m][r];
        secv[base + row]  = sec[m][r];
        besti[base + row] = bidx[m][r];
      }
  }
#undef AM_LOAD
#undef AM_WRITE
}

// ---------------- kernel 3: combine K-slices, flag ambiguous rows
__global__ void k_combine(const float* __restrict__ bestv, const float* __restrict__ secv,
                          const int* __restrict__ besti, int* __restrict__ idx_out,
                          int* __restrict__ list, unsigned int* __restrict__ count, int N) {
  int n = blockIdx.x * blockDim.x + threadIdx.x;
  if (n >= N) return;
  float b = bestv[n], s = secv[n];
  int bi = besti[n];
#pragma unroll
  for (int p = 1; p < KSPLIT; ++p) {
    float ob = bestv[(size_t)p * N + n];
    float os = secv[(size_t)p * N + n];
    int   oi = besti[(size_t)p * N + n];
    if (ob < b || (ob == b && oi < bi)) { s = fminf(b, os); b = ob; bi = oi; }
    else s = fminf(s, ob);
  }
  idx_out[n] = bi;
  if (s - b < MARGIN) {
    unsigned int p = atomicAdd(count, 1u);
    list[p] = n;
  }
}

// ---------------- kernel 4: exact f64 rescan of flagged rows
__global__ void k_rescan(const float* __restrict__ x, const float* __restrict__ e,
                         const double* __restrict__ e2d, const int* __restrict__ list,
                         const unsigned int* __restrict__ count, int* __restrict__ idx_out,
                         int D, int K) {
  __shared__ float xrow[256];
  __shared__ double rv[256];
  __shared__ int ri[256];
  const int tid = threadIdx.x;
  const unsigned int cnt = *count;
  for (unsigned int ii = blockIdx.x; ii < cnt; ii += gridDim.x) {
    const int row = list[ii];
    __syncthreads();
    for (int d = tid; d < D; d += 256) xrow[d] = x[(size_t)row * D + d];
    __syncthreads();
    double bb = 1e300; int bi = 0;
    for (int j = 0; j < K; j += 256) {
      const int k = j + tid;
      double dot = 0.0;
      for (int d = 0; d < D; ++d)
        dot = fma((double)xrow[d], (double)e[(size_t)d * K + k], dot);
      double dist = e2d[k] - 2.0 * dot;
      if (dist < bb || (dist == bb && k < bi)) { bb = dist; bi = k; }
    }
    rv[tid] = bb; ri[tid] = bi;
    __syncthreads();
    for (int off = 128; off > 0; off >>= 1) {
      if (tid < off) {
        if (rv[tid + off] < rv[tid] || (rv[tid + off] == rv[tid] && ri[tid + off] < ri[tid])) {
          rv[tid] = rv[tid + off]; ri[tid] = ri[tid + off];
        }
      }
      __syncthreads();
    }
    if (tid == 0) idx_out[row] = ri[0];
    __syncthreads();
  }
}

// ---------------- kernel 5: histogram + float indices
__global__ void k_hist(const int* __restrict__ idx, unsigned int* __restrict__ cnt,
                       float* __restrict__ idxf_out, int N) {
  int n = blockIdx.x * blockDim.x + threadIdx.x;
  if (n >= N) return;
  int c = idx[n];
  idxf_out[n] = (float)c;
  atomicAdd(&cnt[c], 1u);
}

// ---------------- kernel 6: cluster_size_new, n, smoothed cs
__global__ void k_cluster(const float* __restrict__ cs_in,
                          const unsigned int* __restrict__ cnt,
                          float* __restrict__ out_csn, float* __restrict__ cs_ws,
                          int K) {
  __shared__ double red[256];
  const int tid = threadIdx.x;
  double s = 0.0;
  for (int k = tid; k < K; k += 256) {
    float csn = cs_in[k] * DECAY + (float)cnt[k] * (1.0f - EPS_F);
    out_csn[k] = csn;
    s += (double)csn;
  }
  red[tid] = s;
  __syncthreads();
  for (int off = 128; off > 0; off >>= 1) {
    if (tid < off) red[tid] += red[tid + off];
    __syncthreads();
  }
  const float n = (float)red[0];
  const float denom = n + (float)K * EPS_F;
  for (int k = tid; k < K; k += 256) {
    float csn = out_csn[k];
    cs_ws[k] = (csn + EPS_F) / denom * n;
  }
}

// ---------------- kernel 7: embed_avg_new = avg*decay ; embed_new = avg_new / cs
__global__ void k_embed(const float* __restrict__ avg_in, const float* __restrict__ cs_ws,
                        float* __restrict__ out_avg, float* __restrict__ out_emb, int K) {
  int k = blockIdx.x * blockDim.x + threadIdx.x;
  int d = blockIdx.y;
  if (k >= K) return;
  size_t i = (size_t)d * K + k;
  float a = avg_in[i] * DECAY;
  out_avg[i] = a;
  out_emb[i] = a / cs_ws[k];
}

// ---------------- kernel 8: transpose out_emb [D][K] -> embT [K][D]
__global__ void k_transpose(const float* __restrict__ src, float* __restrict__ dst,
                            int D, int K) {
  __shared__ float t[64][65];
  const int kb = blockIdx.x * 64;
  const int db = blockIdx.y * 64;
  const int c = threadIdx.x & 63;
  const int r0 = (threadIdx.x >> 6) * 16;
  for (int i = 0; i < 16; ++i)
    t[r0 + i][c] = src[(size_t)(db + r0 + i) * K + kb + c];
  __syncthreads();
  for (int i = 0; i < 16; ++i)
    dst[(size_t)(kb + r0 + i) * D + db + c] = t[c][r0 + i];
}

// ---------------- kernel 9: gather quantize + straight-through + diff partial
__global__ void k_gather(const float* __restrict__ x, const float* __restrict__ embT,
                         const int* __restrict__ idx, float* __restrict__ out_q,
                         float* __restrict__ partial) {
  __shared__ float red[256];
  const int tid = threadIdx.x;
  const int n0 = blockIdx.x * 64;
  float s = 0.f;
  for (int u = 0; u < 16; ++u) {
    int i = u * 256 + tid;
    int row = n0 + (i >> 6);
    int f4 = (i & 63) * 4;
    int code = idx[row];
    float4 q  = *(const float4*)&embT[(size_t)code * D_FIX + f4];
    float4 xv = *(const float4*)&x[(size_t)row * D_FIX + f4];
    float4 dv = {q.x - xv.x, q.y - xv.y, q.z - xv.z, q.w - xv.w};
    float4 val = {xv.x + dv.x, xv.y + dv.y, xv.z + dv.z, xv.w + dv.w};
    *(float4*)&out_q[(size_t)row * D_FIX + f4] = val;
    s += dv.x * dv.x + dv.y * dv.y + dv.z * dv.z + dv.w * dv.w;
  }
  red[tid] = s;
  __syncthreads();
  for (int off = 128; off > 0; off >>= 1) {
    if (tid < off) red[tid] += red[tid + off];
    __syncthreads();
  }
  if (tid == 0) partial[blockIdx.x] = red[0];
}

// ---------------- kernel 10: diff = mean
__global__ void k_diff(const float* __restrict__ partial, float* __restrict__ out_diff,
                       int NB, long long total) {
  __shared__ double red[256];
  const int tid = threadIdx.x;
  double s = 0.0;
  for (int i = tid; i < NB; i += 256) s += (double)partial[i];
  red[tid] = s;
  __syncthreads();
  for (int off = 128; off > 0; off >>= 1) {
    if (tid < off) red[tid] += red[tid + off];
    __syncthreads();
  }
  if (tid == 0) out_diff[0] = (float)(red[0] / (double)total);
}

extern "C" void kernel_launch(void* const* d_in, const int* in_sizes, int n_in,
                              void* d_out, int out_size, void* d_ws, size_t ws_size,
                              hipStream_t stream) {
  const float* x            = (const float*)d_in[0];
  const float* embed        = (const float*)d_in[1];
  const float* cluster_size = (const float*)d_in[2];
  const float* embed_avg    = (const float*)d_in[3];

  const int K = in_sizes[2];
  const int D = in_sizes[1] / K;      // 256
  const int N = in_sizes[0] / D;      // 32768

  float* out      = (float*)d_out;
  float* out_q    = out;                          // N*D
  float* out_idx  = out_q + (size_t)N * D;        // N (indices as float)
  float* out_diff = out_idx + N;                  // 1
  float* out_csn  = out_diff + 1;                 // K
  float* out_avg  = out_csn + K;                  // D*K
  float* out_emb  = out_avg + (size_t)D * K;      // D*K

  char* ws = (char*)d_ws;
  double*       e2d     = (double*)ws;               ws += (size_t)K * 8;
  float*        e2f     = (float*)ws;                ws += (size_t)K * 4;
  int*          idx     = (int*)ws;                  ws += (size_t)N * 4;
  unsigned int* cnt     = (unsigned int*)ws;         ws += (size_t)K * 4;
  float*        cs_ws   = (float*)ws;                ws += (size_t)K * 4;
  float*        partial = (float*)ws;                ws += (size_t)(N / 64) * 4;
  float*        bestv   = (float*)ws;                ws += (size_t)KSPLIT * N * 4;
  float*        secv    = (float*)ws;                ws += (size_t)KSPLIT * N * 4;
  int*          besti   = (int*)ws;                  ws += (size_t)KSPLIT * N * 4;
  int*          list    = (int*)ws;                  ws += (size_t)N * 4;
  unsigned int* count   = (unsigned int*)ws;         ws += 64;
  float*        embT    = (float*)ws;                ws += (size_t)K * D * 4;

  hipMemsetAsync(cnt, 0, (size_t)K * sizeof(unsigned int), stream);
  hipMemsetAsync(count, 0, sizeof(unsigned int), stream);

  k_enorm<<<dim3(K / 64), dim3(256), 0, stream>>>(embed, e2d, e2f, D, K);
  k_argmin_mfma<<<dim3(N / BM, KSPLIT), dim3(256), 0, stream>>>(x, embed, e2f, bestv, secv,
                                                                besti, N, K);
  k_combine<<<dim3((N + 255) / 256), dim3(256), 0, stream>>>(bestv, secv, besti, idx,
                                                             list, count, N);
  k_rescan<<<dim3(256), dim3(256), 0, stream>>>(x, embed, e2d, list, count, idx, D, K);
  k_hist<<<dim3((N + 255) / 256), dim3(256), 0, stream>>>(idx, cnt, out_idx, N);
  k_cluster<<<dim3(1), dim3(256), 0, stream>>>(cluster_size, cnt, out_csn, cs_ws, K);
  k_embed<<<dim3((K + 255) / 256, D), dim3(256), 0, stream>>>(embed_avg, cs_ws, out_avg, out_emb, K);
  k_transpose<<<dim3(K / 64, D / 64), dim3(256), 0, stream>>>(out_emb, embT, D, K);
  k_gather<<<dim3(N / 64), dim3(256), 0, stream>>>(x, embT, idx, out_q, partial);
  k_diff<<<dim3(1), dim3(256), 0, stream>>>(partial, out_diff, N / 64, (long long)N * D);
}

// Round 4
// 454.530 us; speedup vs baseline: 7.6824x; 3.9832x over previous
//
#include <hip/hip_runtime.h>
#include <math.h>

constexpr float DECAY = 0.99f;
constexpr float EPS_F = 1e-5f;
constexpr float MARGIN = 0.08f;   // bf16-split worst-case err ~0.02/side; 2x safety

typedef short bf16x8 __attribute__((ext_vector_type(8)));
typedef float f32x4 __attribute__((ext_vector_type(4)));

#define BM 128      // rows per block
#define BN 64       // codes per k-tile
#define KSPLIT 4    // K/KSPLIT codes scanned per block
#define D_FIX 256

__device__ __forceinline__ unsigned rne_bf16(float f) {
  unsigned u = __float_as_uint(f);
  return (u + 0x7fffu + ((u >> 16) & 1u)) >> 16;
}
// split f32 -> hi (truncated top16) | lo (RNE bf16 of remainder), packed in u32
__device__ __forceinline__ unsigned pack_hilo(float v) {
  unsigned u = __float_as_uint(v);
  unsigned hi = u & 0xffff0000u;
  float rem = v - __uint_as_float(hi);
  return hi | rne_bf16(rem);
}

// ---------------- kernel 1: e2[k] = sum_d e[d,k]^2  (f64 exact + f32 copy)
__global__ void k_enorm(const float* __restrict__ e, double* __restrict__ e2d,
                        float* __restrict__ e2f, int D, int K) {
  __shared__ double red[4][64];
  const int kl = threadIdx.x & 63;
  const int part = threadIdx.x >> 6;
  const int k = blockIdx.x * 64 + kl;
  double s = 0.0;
  for (int d = part; d < D; d += 4) {
    double v = (double)e[(size_t)d * K + k];
    s = fma(v, v, s);
  }
  red[part][kl] = s;
  __syncthreads();
  if (part == 0) {
    double t = ((red[0][kl] + red[1][kl]) + red[2][kl]) + red[3][kl];
    e2d[k] = t;
    e2f[k] = (float)t;
  }
}

// ---------------- kernel 2: MFMA bf16-split top-2 argmin over a K-slice
__launch_bounds__(256, 2)
__global__ void k_argmin_mfma(const float* __restrict__ x, const float* __restrict__ e,
                              const float* __restrict__ e2f,
                              float* __restrict__ bestv, float* __restrict__ secv,
                              int* __restrict__ besti, int N, int K) {
  // E slice: 32 d x 64 cols, packed hi|lo u32, TRANSPOSED [col][d-word],
  // 16B chunks XOR-swizzled by (col&7) for conflict-free ds_read_b128.
  __shared__ unsigned es[2][BN][32];
  __shared__ float e2s[1024];      // this block's K-slice of ||e||^2

  const int tid = threadIdx.x;
  const int w   = tid >> 6;        // wave 0..3
  const int l   = tid & 63;
  const int g   = l >> 4;          // lane group 0..3
  const int c16 = l & 15;
  const int kslice = K / KSPLIT;   // 1024
  const int kbase  = blockIdx.y * kslice;
  const int rowW   = blockIdx.x * BM + w * 32;   // wave's 32 rows

  // stage e2 slice
  for (int i = tid; i < 1024; i += 256) e2s[i] = e2f[kbase + i];

  // ---- X fragments in registers: rows rowW + m*16 + c16, d = t*32 + 8g + e
  bf16x8 xh[2][8], xl[2][8];
#pragma unroll
  for (int m = 0; m < 2; ++m) {
    const float* xr = x + (size_t)(rowW + m * 16 + c16) * D_FIX + 8 * g;
#pragma unroll
    for (int t = 0; t < 8; ++t) {
      float4 fa = *(const float4*)(xr + t * 32);
      float4 fb = *(const float4*)(xr + t * 32 + 4);
      float f[8] = {fa.x, fa.y, fa.z, fa.w, fb.x, fb.y, fb.z, fb.w};
      union { unsigned u[4]; bf16x8 v; } H, L;
#pragma unroll
      for (int p = 0; p < 4; ++p) {
        unsigned w0 = pack_hilo(f[2 * p]);
        unsigned w1 = pack_hilo(f[2 * p + 1]);
        H.u[p] = (w0 >> 16) | (w1 & 0xffff0000u);
        L.u[p] = (w0 & 0xffffu) | (w1 << 16);
      }
      xh[m][t] = H.v;
      xl[m][t] = L.v;
    }
  }

  float best[2][4], sec[2][4];
  int bidx[2][4];
#pragma unroll
  for (int m = 0; m < 2; ++m)
#pragma unroll
    for (int r = 0; r < 4; ++r) { best[m][r] = 3e38f; sec[m][r] = 3e38f; bidx[m][r] = 0; }

  // ---- staging helpers (inline): step s covers kt = s>>3 (64 cols), dd=(s&7)*32
  float la[4][4];
  const int sq  = tid & 7;                // d-quad 0..7
  const int scq = 4 * ((tid >> 3) & 15);  // col-quad 0..60
  const bool stager = (tid < 128);

#define AM_LOAD(s_)                                                            \
  if (stager) {                                                                \
    const float* src = e + (size_t)(((s_) & 7) * 32 + sq * 4) * K              \
                         + (kbase + ((s_) >> 3) * 64 + scq);                   \
    _Pragma("unroll")                                                          \
    for (int i_ = 0; i_ < 4; ++i_) {                                           \
      float4 v_ = *(const float4*)(src + (size_t)i_ * K);                      \
      la[i_][0] = v_.x; la[i_][1] = v_.y; la[i_][2] = v_.z; la[i_][3] = v_.w;  \
    }                                                                          \
  }

#define AM_WRITE(buf_)                                                         \
  if (stager) {                                                                \
    _Pragma("unroll")                                                          \
    for (int j_ = 0; j_ < 4; ++j_) {                                           \
      int col_ = scq + j_;                                                     \
      uint4 pw_;                                                               \
      pw_.x = pack_hilo(la[0][j_]); pw_.y = pack_hilo(la[1][j_]);              \
      pw_.z = pack_hilo(la[2][j_]); pw_.w = pack_hilo(la[3][j_]);              \
      *(uint4*)&es[buf_][col_][(sq ^ (col_ & 7)) * 4] = pw_;                   \
    }                                                                          \
  }

  AM_LOAD(0);
  AM_WRITE(0);
  AM_LOAD(1);
  __syncthreads();

  int buf = 0;
  const int sw = c16 & 7;

  for (int kt = 0; kt < 16; ++kt) {
    f32x4 acc[2][4];
#pragma unroll
    for (int m = 0; m < 2; ++m)
#pragma unroll
      for (int c = 0; c < 4; ++c) acc[m][c] = (f32x4){0.f, 0.f, 0.f, 0.f};

#pragma unroll
    for (int t = 0; t < 8; ++t) {
      // compute on es[buf]
#pragma unroll
      for (int c = 0; c < 4; ++c) {
        const int col = c * 16 + c16;
        const unsigned* ep = es[buf][col];
        uint4 q0 = *(const uint4*)&ep[((2 * g) ^ sw) * 4];
        uint4 q1 = *(const uint4*)&ep[((2 * g + 1) ^ sw) * 4];
        union { unsigned u[4]; bf16x8 v; } bh, bl;
        bh.u[0] = (q0.y & 0xffff0000u) | (q0.x >> 16);
        bl.u[0] = (q0.x & 0xffffu) | (q0.y << 16);
        bh.u[1] = (q0.w & 0xffff0000u) | (q0.z >> 16);
        bl.u[1] = (q0.z & 0xffffu) | (q0.w << 16);
        bh.u[2] = (q1.y & 0xffff0000u) | (q1.x >> 16);
        bl.u[2] = (q1.x & 0xffffu) | (q1.y << 16);
        bh.u[3] = (q1.w & 0xffff0000u) | (q1.z >> 16);
        bl.u[3] = (q1.z & 0xffffu) | (q1.w << 16);
#pragma unroll
        for (int m = 0; m < 2; ++m) {
          acc[m][c] = __builtin_amdgcn_mfma_f32_16x16x32_bf16(xh[m][t], bh.v, acc[m][c], 0, 0, 0);
          acc[m][c] = __builtin_amdgcn_mfma_f32_16x16x32_bf16(xh[m][t], bl.v, acc[m][c], 0, 0, 0);
          acc[m][c] = __builtin_amdgcn_mfma_f32_16x16x32_bf16(xl[m][t], bh.v, acc[m][c], 0, 0, 0);
        }
      }
      const int s = kt * 8 + t;
      if (s < 127) { AM_WRITE(buf ^ 1); }
      if (s < 126) { AM_LOAD(s + 2); }
      __syncthreads();
      buf ^= 1;
    }

    // fold k-tile into running top-2 (k ascending => strict < keeps smallest k)
#pragma unroll
    for (int c = 0; c < 4; ++c) {
      const int klocal = kt * 64 + c * 16 + c16;
      const float e2v = e2s[klocal];
      const int kg = kbase + klocal;
#pragma unroll
      for (int m = 0; m < 2; ++m)
#pragma unroll
        for (int r = 0; r < 4; ++r) {
          float dist = fmaf(-2.f, acc[m][c][r], e2v);
          if (dist < best[m][r]) { sec[m][r] = best[m][r]; best[m][r] = dist; bidx[m][r] = kg; }
          else sec[m][r] = fminf(sec[m][r], dist);
        }
    }
  }

  // merge top-2 across the 16 col lanes (same row)
#pragma unroll
  for (int off = 1; off < 16; off <<= 1) {
#pragma unroll
    for (int m = 0; m < 2; ++m)
#pragma unroll
      for (int r = 0; r < 4; ++r) {
        float ob = __shfl_xor(best[m][r], off);
        float os = __shfl_xor(sec[m][r], off);
        int   oi = __shfl_xor(bidx[m][r], off);
        if (ob < best[m][r] || (ob == best[m][r] && oi < bidx[m][r])) {
          sec[m][r] = fminf(best[m][r], os); best[m][r] = ob; bidx[m][r] = oi;
        } else {
          sec[m][r] = fminf(sec[m][r], ob);
        }
      }
  }

  if (c16 == 0) {
    const size_t base = (size_t)blockIdx.y * N;
#pragma unroll
    for (int m = 0; m < 2; ++m)
#pragma unroll
      for (int r = 0; r < 4; ++r) {
        int row = rowW + m * 16 + 4 * g + r;
        bestv[base + row] = best[m][r];
        secv[base + row]  = sec[m][r];
        besti[base + row] = bidx[m][r];
      }
  }
#undef AM_LOAD
#undef AM_WRITE
}

// ---------------- kernel 3: combine K-slices, flag ambiguous rows
__global__ void k_combine(const float* __restrict__ bestv, const float* __restrict__ secv,
                          const int* __restrict__ besti, int* __restrict__ idx_out,
                          int* __restrict__ list, unsigned int* __restrict__ count, int N) {
  int n = blockIdx.x * blockDim.x + threadIdx.x;
  if (n >= N) return;
  float b = bestv[n], s = secv[n];
  int bi = besti[n];
#pragma unroll
  for (int p = 1; p < KSPLIT; ++p) {
    float ob = bestv[(size_t)p * N + n];
    float os = secv[(size_t)p * N + n];
    int   oi = besti[(size_t)p * N + n];
    if (ob < b || (ob == b && oi < bi)) { s = fminf(b, os); b = ob; bi = oi; }
    else s = fminf(s, ob);
  }
  idx_out[n] = bi;
  if (s - b < MARGIN) {
    unsigned int p = atomicAdd(count, 1u);
    list[p] = n;
  }
}

// ---------------- kernel 4: exact f64 rescan of flagged rows (throughput form)
__launch_bounds__(256, 4)
__global__ void k_rescan(const float* __restrict__ x, const float* __restrict__ e,
                         const double* __restrict__ e2d, const int* __restrict__ list,
                         const unsigned int* __restrict__ count, int* __restrict__ idx_out,
                         int K) {
  __shared__ double xrow[D_FIX];
  __shared__ double rv[256];
  __shared__ int ri[256];
  const int tid = threadIdx.x;
  const unsigned int cnt = *count;
  for (unsigned int ii = blockIdx.x; ii < cnt; ii += gridDim.x) {
    const int row = list[ii];
    __syncthreads();
    xrow[tid] = (double)x[(size_t)row * D_FIX + tid];
    __syncthreads();
    double bb = 1e300; int bi = 0;
    for (int j = 0; j < K; j += 256) {
      const int k = j + tid;
      const float* ek = e + k;
      double a0 = 0.0, a1 = 0.0, a2 = 0.0, a3 = 0.0;
#pragma unroll 8
      for (int d = 0; d < D_FIX; d += 4) {
        a0 = fma(xrow[d + 0], (double)ek[(size_t)(d + 0) * K], a0);
        a1 = fma(xrow[d + 1], (double)ek[(size_t)(d + 1) * K], a1);
        a2 = fma(xrow[d + 2], (double)ek[(size_t)(d + 2) * K], a2);
        a3 = fma(xrow[d + 3], (double)ek[(size_t)(d + 3) * K], a3);
      }
      double dist = e2d[k] - 2.0 * ((a0 + a1) + (a2 + a3));
      if (dist < bb || (dist == bb && k < bi)) { bb = dist; bi = k; }
    }
    rv[tid] = bb; ri[tid] = bi;
    __syncthreads();
    for (int off = 128; off > 0; off >>= 1) {
      if (tid < off) {
        if (rv[tid + off] < rv[tid] || (rv[tid + off] == rv[tid] && ri[tid + off] < ri[tid])) {
          rv[tid] = rv[tid + off]; ri[tid] = ri[tid + off];
        }
      }
      __syncthreads();
    }
    if (tid == 0) idx_out[row] = ri[0];
    __syncthreads();
  }
}

// ---------------- kernel 5: histogram + float indices
__global__ void k_hist(const int* __restrict__ idx, unsigned int* __restrict__ cnt,
                       float* __restrict__ idxf_out, int N) {
  int n = blockIdx.x * blockDim.x + threadIdx.x;
  if (n >= N) return;
  int c = idx[n];
  idxf_out[n] = (float)c;
  atomicAdd(&cnt[c], 1u);
}

// ---------------- kernel 6: cluster_size_new, n, smoothed cs
__global__ void k_cluster(const float* __restrict__ cs_in,
                          const unsigned int* __restrict__ cnt,
                          float* __restrict__ out_csn, float* __restrict__ cs_ws,
                          int K) {
  __shared__ double red[256];
  const int tid = threadIdx.x;
  double s = 0.0;
  for (int k = tid; k < K; k += 256) {
    float csn = cs_in[k] * DECAY + (float)cnt[k] * (1.0f - EPS_F);
    out_csn[k] = csn;
    s += (double)csn;
  }
  red[tid] = s;
  __syncthreads();
  for (int off = 128; off > 0; off >>= 1) {
    if (tid < off) red[tid] += red[tid + off];
    __syncthreads();
  }
  const float n = (float)red[0];
  const float denom = n + (float)K * EPS_F;
  for (int k = tid; k < K; k += 256) {
    float csn = out_csn[k];
    cs_ws[k] = (csn + EPS_F) / denom * n;
  }
}

// ---------------- kernel 7: embed_avg_new = avg*decay ; embed_new = avg_new / cs
__global__ void k_embed(const float* __restrict__ avg_in, const float* __restrict__ cs_ws,
                        float* __restrict__ out_avg, float* __restrict__ out_emb, int K) {
  int k = blockIdx.x * blockDim.x + threadIdx.x;
  int d = blockIdx.y;
  if (k >= K) return;
  size_t i = (size_t)d * K + k;
  float a = avg_in[i] * DECAY;
  out_avg[i] = a;
  out_emb[i] = a / cs_ws[k];
}

// ---------------- kernel 8: transpose out_emb [D][K] -> embT [K][D]
__global__ void k_transpose(const float* __restrict__ src, float* __restrict__ dst,
                            int D, int K) {
  __shared__ float t[64][65];
  const int kb = blockIdx.x * 64;
  const int db = blockIdx.y * 64;
  const int c = threadIdx.x & 63;
  const int r0 = (threadIdx.x >> 6) * 16;
  for (int i = 0; i < 16; ++i)
    t[r0 + i][c] = src[(size_t)(db + r0 + i) * K + kb + c];
  __syncthreads();
  for (int i = 0; i < 16; ++i)
    dst[(size_t)(kb + r0 + i) * D + db + c] = t[c][r0 + i];
}

// ---------------- kernel 9: gather quantize + straight-through + diff partial
__global__ void k_gather(const float* __restrict__ x, const float* __restrict__ embT,
                         const int* __restrict__ idx, float* __restrict__ out_q,
                         float* __restrict__ partial) {
  __shared__ float red[256];
  const int tid = threadIdx.x;
  const int n0 = blockIdx.x * 64;
  float s = 0.f;
  for (int u = 0; u < 16; ++u) {
    int i = u * 256 + tid;
    int row = n0 + (i >> 6);
    int f4 = (i & 63) * 4;
    int code = idx[row];
    float4 q  = *(const float4*)&embT[(size_t)code * D_FIX + f4];
    float4 xv = *(const float4*)&x[(size_t)row * D_FIX + f4];
    float4 dv = {q.x - xv.x, q.y - xv.y, q.z - xv.z, q.w - xv.w};
    float4 val = {xv.x + dv.x, xv.y + dv.y, xv.z + dv.z, xv.w + dv.w};
    *(float4*)&out_q[(size_t)row * D_FIX + f4] = val;
    s += dv.x * dv.x + dv.y * dv.y + dv.z * dv.z + dv.w * dv.w;
  }
  red[tid] = s;
  __syncthreads();
  for (int off = 128; off > 0; off >>= 1) {
    if (tid < off) red[tid] += red[tid + off];
    __syncthreads();
  }
  if (tid == 0) partial[blockIdx.x] = red[0];
}

// ---------------- kernel 10: diff = mean
__global__ void k_diff(const float* __restrict__ partial, float* __restrict__ out_diff,
                       int NB, long long total) {
  __shared__ double red[256];
  const int tid = threadIdx.x;
  double s = 0.0;
  for (int i = tid; i < NB; i += 256) s += (double)partial[i];
  red[tid] = s;
  __syncthreads();
  for (int off = 128; off > 0; off >>= 1) {
    if (tid < off) red[tid] += red[tid + off];
    __syncthreads();
  }
  if (tid == 0) out_diff[0] = (float)(red[0] / (double)total);
}

extern "C" void kernel_launch(void* const* d_in, const int* in_sizes, int n_in,
                              void* d_out, int out_size, void* d_ws, size_t ws_size,
                              hipStream_t stream) {
  const float* x            = (const float*)d_in[0];
  const float* embed        = (const float*)d_in[1];
  const float* cluster_size = (const float*)d_in[2];
  const float* embed_avg    = (const float*)d_in[3];

  const int K = in_sizes[2];
  const int D = in_sizes[1] / K;      // 256
  const int N = in_sizes[0] / D;      // 32768

  float* out      = (float*)d_out;
  float* out_q    = out;                          // N*D
  float* out_idx  = out_q + (size_t)N * D;        // N (indices as float)
  float* out_diff = out_idx + N;                  // 1
  float* out_csn  = out_diff + 1;                 // K
  float* out_avg  = out_csn + K;                  // D*K
  float* out_emb  = out_avg + (size_t)D * K;      // D*K

  char* ws = (char*)d_ws;
  double*       e2d     = (double*)ws;               ws += (size_t)K * 8;
  float*        e2f     = (float*)ws;                ws += (size_t)K * 4;
  int*          idx     = (int*)ws;                  ws += (size_t)N * 4;
  unsigned int* cnt     = (unsigned int*)ws;         ws += (size_t)K * 4;
  float*        cs_ws   = (float*)ws;                ws += (size_t)K * 4;
  float*        partial = (float*)ws;                ws += (size_t)(N / 64) * 4;
  float*        bestv   = (float*)ws;                ws += (size_t)KSPLIT * N * 4;
  float*        secv    = (float*)ws;                ws += (size_t)KSPLIT * N * 4;
  int*          besti   = (int*)ws;                  ws += (size_t)KSPLIT * N * 4;
  int*          list    = (int*)ws;                  ws += (size_t)N * 4;
  unsigned int* count   = (unsigned int*)ws;         ws += 64;
  float*        embT    = (float*)ws;                ws += (size_t)K * D * 4;

  hipMemsetAsync(cnt, 0, (size_t)K * sizeof(unsigned int), stream);
  hipMemsetAsync(count, 0, sizeof(unsigned int), stream);

  k_enorm<<<dim3(K / 64), dim3(256), 0, stream>>>(embed, e2d, e2f, D, K);
  k_argmin_mfma<<<dim3(N / BM, KSPLIT), dim3(256), 0, stream>>>(x, embed, e2f, bestv, secv,
                                                                besti, N, K);
  k_combine<<<dim3((N + 255) / 256), dim3(256), 0, stream>>>(bestv, secv, besti, idx,
                                                             list, count, N);
  k_rescan<<<dim3(1024), dim3(256), 0, stream>>>(x, embed, e2d, list, count, idx, K);
  k_hist<<<dim3((N + 255) / 256), dim3(256), 0, stream>>>(idx, cnt, out_idx, N);
  k_cluster<<<dim3(1), dim3(256), 0, stream>>>(cluster_size, cnt, out_csn, cs_ws, K);
  k_embed<<<dim3((K + 255) / 256, D), dim3(256), 0, stream>>>(embed_avg, cs_ws, out_avg, out_emb, K);
  k_transpose<<<dim3(K / 64, D / 64), dim3(256), 0, stream>>>(out_emb, embT, D, K);
  k_gather<<<dim3(N / 64), dim3(256), 0, stream>>>(x, embT, idx, out_q, partial);
  k_diff<<<dim3(1), dim3(256), 0, stream>>>(partial, out_diff, N / 64, (long long)N * D);
}